// Round 8
// baseline (325.411 us; speedup 1.0000x reference)
//
#include <hip/hip_runtime.h>
#include <math.h>

typedef short bf16x8 __attribute__((ext_vector_type(8)));
typedef float f32x4 __attribute__((ext_vector_type(4)));

#define HH 8
#define NN 4096
#define DIP 256   // ip(240) + s(16), no pad
#define DDX 256   // qdx: [hi|hi | mid|lo | mid32-47+16z | hi32-47+16z]
#define DKM 192   // kmx: [mid | lo | hi | hi]
#define DV 272
#define BN 32
#define NT (NN/BN)

typedef const __attribute__((address_space(1))) unsigned int* gp_t;
typedef __attribute__((address_space(3))) unsigned int* lp_t;
__device__ __forceinline__ void gload16(const void* g, void* l) {
    __builtin_amdgcn_global_load_lds((gp_t)g, (lp_t)l, 16, 0, 0);
}

__device__ __forceinline__ unsigned short f2bf(float f) {
    unsigned int u = __float_as_uint(f);
    u = (u + 0x7fffu + ((u >> 16) & 1u)) >> 16;   // RNE
    return (unsigned short)u;
}
__device__ __forceinline__ float bf2f(unsigned short h) {
    return __uint_as_float(((unsigned int)h) << 16);
}

// ---- stage 1a: features. fip[256] = ip+s. fdx: Q-mode 256 cols / K-mode 192 cols ----
__global__ void feat_kernel(const float* __restrict__ mv,
                            const float* __restrict__ sv,
                            const float* __restrict__ basis,
                            float scale, int qmode,
                            unsigned short* __restrict__ fip,
                            unsigned short* __restrict__ fdx)
{
    __shared__ float sb[150];
    int t = threadIdx.x;
    if (t < 150) sb[t] = basis[t];
    __syncthreads();
    int row = blockIdx.x * 32 + (t >> 3);   // (h*4096+n)
    int c = t & 7;
    const float* m = mv + (size_t)row * 256 + c * 32;
    float f[32];
    #pragma unroll
    for (int i = 0; i < 8; ++i) {
        float4 v = ((const float4*)m)[i];
        f[i*4+0] = v.x; f[i*4+1] = v.y; f[i*4+2] = v.z; f[i*4+3] = v.w;
    }
    unsigned short* ip = fip + (size_t)row * DIP;
    unsigned short* dx = fdx + (size_t)row * (qmode ? DDX : DKM);
    #pragma unroll
    for (int j = 0; j < 30; ++j)
        ip[c*30 + j] = f2bf(f[1+j] * scale);
    if (c < 2) {
        #pragma unroll
        for (int i = 0; i < 8; ++i)
            ip[240 + c*8 + i] = f2bf(sv[(size_t)row*16 + c*8 + i] * scale);
    }
    float nn = 1.0f / sqrtf(f[5]*f[5] + 0.001f);
    float tn[5];
    #pragma unroll
    for (int x = 0; x < 5; ++x) tn[x] = f[1+x] * nn;
    #pragma unroll
    for (int z = 0; z < 6; ++z) {
        float acc = 0.f;
        #pragma unroll
        for (int x = 0; x < 5; ++x) {
            #pragma unroll
            for (int y = 0; y < 5; ++y)
                acc = fmaf(sb[(x*5+y)*6 + z] * tn[x], tn[y], acc);
        }
        acc *= scale;
        unsigned short hi = f2bf(acc);
        float r1 = acc - bf2f(hi);
        unsigned short mi = f2bf(r1);
        float r2 = r1 - bf2f(mi);
        unsigned short lo = f2bf(r2);
        int cz = c*6 + z;
        if (qmode) {
            dx[cz]      = hi;  dx[48 + cz]  = hi;
            dx[96 + cz] = mi;  dx[144 + cz] = lo;
            if (cz < 16) { dx[208 + cz] = 0; dx[240 + cz] = 0; }
            if (cz >= 32) { dx[160 + cz] = mi; dx[192 + cz] = hi; }
        } else {
            dx[cz]      = mi;  dx[48 + cz]  = lo;
            dx[96 + cz] = hi;  dx[144 + cz] = hi;
        }
    }
}

// ---- stage 1b: V -> transposed bf16 [8][272][4096] ----
__global__ void vtrans_kernel(const float* __restrict__ vmv,
                              const float* __restrict__ vs,
                              unsigned short* __restrict__ dst)
{
    __shared__ unsigned short tile[64][DV];
    int blk = blockIdx.x;
    int h = blk >> 6;
    int n0 = (blk & 63) << 6;
    int t = threadIdx.x;
    #pragma unroll
    for (int it = 0; it < 16; ++it) {
        int v = t + it*256;
        int r = v >> 6;
        int sg = v & 63;
        float4 x = *(const float4*)(vmv + ((size_t)(h*NN + n0 + r))*256 + sg*4);
        tile[r][sg*4+0] = f2bf(x.x);
        tile[r][sg*4+1] = f2bf(x.y);
        tile[r][sg*4+2] = f2bf(x.z);
        tile[r][sg*4+3] = f2bf(x.w);
    }
    #pragma unroll
    for (int it = 0; it < 4; ++it) {
        int v = t + it*256;
        int r = v >> 4;
        int si = v & 15;
        tile[r][256 + si] = f2bf(vs[((size_t)(h*NN + n0 + r))*16 + si]);
    }
    __syncthreads();
    #pragma unroll
    for (int it = 0; it < 17; ++it) {
        int v = t + it*256;
        int dd = v >> 4;
        int sg = v & 15;
        ushort4 o;
        o.x = tile[sg*4+0][dd];
        o.y = tile[sg*4+1][dd];
        o.z = tile[sg*4+2][dd];
        o.w = tile[sg*4+3][dd];
        *(ushort4*)(dst + ((size_t)(h*DV + dd))*NN + n0 + sg*4) = o;
    }
}

// ---- stage 2: flash attention, 8-wave block, full dbuf, 2 barriers/tile ----
__global__ __launch_bounds__(512, 1)
void attn_kernel(const unsigned short* __restrict__ Qip,
                 const unsigned short* __restrict__ Qdx,
                 const unsigned short* __restrict__ Kip,
                 const unsigned short* __restrict__ Kmx,
                 const unsigned short* __restrict__ Vt,
                 float* __restrict__ out)
{
    // LDS (ush): kt 2x8192 [0,16384) | kmx 2x6144 [16384,28672) | vt 2x8704 [28672,46080) | pb 4096 [46080,50176)
    __shared__ __align__(128) unsigned short smem[50176];   // 100,352 B

    int blk = blockIdx.x;
    int sbk = ((blk & 7) << 5) | (blk >> 3);   // grid 256, bijective XCD swizzle; XCD x = head x
    int h = sbk >> 5;
    int q0 = (sbk & 31) * 128;
    int tid = threadIdx.x;
    int w = tid >> 6;
    int lane = tid & 63;
    int l15 = lane & 15;
    int l4 = lane >> 4;
    int l7l = l15 & 3;
    int l7h = (l15 >> 2) & 1;

    // Q fragments (B-operand: col=q=l15, dims l4*8..)
    const unsigned short* qipr = Qip + (size_t)(h*NN + q0 + w*16 + l15) * DIP + l4*8;
    const unsigned short* qdxr = Qdx + (size_t)(h*NN + q0 + w*16 + l15) * DDX + l4*8;
    bf16x8 qip[8], qdx[8];
    #pragma unroll
    for (int ks = 0; ks < 8; ++ks) qip[ks] = *(const bf16x8*)(qipr + ks*32);
    #pragma unroll
    for (int ks = 0; ks < 8; ++ks) qdx[ks] = *(const bf16x8*)(qdxr + ks*32);

    // LDS read bases (bytes)
    int cl16 = (l4 ^ l7l) * 16;
    int kbE = l15*512 + cl16 + l7h*64;
    int kbO = l15*512 + cl16 + 64 - l7h*64;
    int mA  = l15*384 + cl16 + l7h*64;
    int mB  = l15*384 + cl16 + 64 - l7h*64;
    int vlane = (l15>>1)*128 + (((((l15&1)<<2) | l4) ^ (l15>>1)) << 4);
    int pbR = 92160 + w*1024 + l15*64;
    int pSeg0 = pbR + ((((l4>>1)    ) ^ l7l) << 4) + (l4&1)*8;
    int pSeg1 = pbR + ((((l4>>1) + 2) ^ l7l) << 4) + (l4&1)*8;
    int pRd   = pbR + ((l4 ^ l7l) << 4);

    // DMA source offsets (ush), loop-invariant. Unified slot map:
    // kt slots [0,1024) | kmx slots [0,768) | vt slots [0,1088)
    int kt0s, kt1s, km0s, km1vt, vt1s, vt2s;
#define KTFL(SLOT, DST) { int r_ = (SLOT) >> 5, fp_ = (SLOT) & 31; \
    int fl_ = (fp_ & 24) | ((((fp_>>2)&1) ^ ((r_>>2)&1)) << 2) | ((fp_&3) ^ (r_&3)); \
    DST = r_*DIP + fl_*8; }
#define KMFL(SLOT, DST) { int r_ = (SLOT)/24, fp_ = (SLOT)%24; \
    int g_ = fp_>>3, po_ = fp_&7; \
    int pl_ = ((((po_>>2)&1) ^ ((r_>>2)&1)) << 2) | ((po_&3) ^ (r_&3)); \
    DST = r_*DKM + (g_*8 + pl_)*8; }
#define VTF(SLOT, DST) { int ch_ = (SLOT) >> 3, ws_ = (SLOT) & 7; int lw_ = ws_ ^ (ch_&7); \
    DST = (ch_*2 + (lw_>>2))*NN + (lw_&3)*8; }
    KTFL(tid, kt0s) KTFL(tid+512, kt1s)
    KMFL(tid, km0s)
    if (tid < 256) { KMFL(tid+512, km1vt) } else { VTF(tid-256, km1vt) }
    VTF(tid+256, vt1s)
    VTF(tid+768, vt2s)
#undef KTFL
#undef KMFL
#undef VTF

    const unsigned short* kiph = Kip + (size_t)h*NN*DIP;
    const unsigned short* kmxh = Kmx + (size_t)h*NN*DKM;
    const unsigned short* vh   = Vt  + (size_t)h*DV*NN;

    f32x4 zero = {0.f, 0.f, 0.f, 0.f};
    f32x4 oacc[17];
    #pragma unroll
    for (int ct = 0; ct < 17; ++ct) oacc[ct] = zero;
    float mreg = -__builtin_inff();
    float lreg = 0.f;

    // per-wave DMA counts: waves 0-4 issue 6, waves 5-7 issue 5
#define ISSUE(TILE, BUF) do { \
    const unsigned short* ks_ = kiph + (size_t)(TILE)*BN*DIP; \
    const unsigned short* ms_ = kmxh + (size_t)(TILE)*BN*DKM; \
    const unsigned short* vs_ = vh + (TILE)*BN; \
    unsigned short* ktd_ = smem + (BUF)*8192; \
    unsigned short* kmd_ = smem + 16384 + (BUF)*6144; \
    unsigned short* vtd_ = smem + 28672 + (BUF)*8704; \
    gload16(ks_ + kt0s, ktd_ + tid*8); \
    gload16(ks_ + kt1s, ktd_ + (tid+512)*8); \
    gload16(ms_ + km0s, kmd_ + tid*8); \
    if (tid < 256) gload16(ms_ + km1vt, kmd_ + (512+tid)*8); \
    else           gload16(vs_ + km1vt, vtd_ + (tid-256)*8); \
    gload16(vs_ + vt1s, vtd_ + (tid+256)*8); \
    if (tid < 320) gload16(vs_ + vt2s, vtd_ + (tid+768)*8); \
} while (0)

    ISSUE(0, 0);
    int cur = 0;
    #pragma unroll 1
    for (int t = 0; t < NT; ++t) {
        if (t < NT-1) ISSUE(t+1, cur^1);    // overwrite-safe: end-barrier of t-1 passed
        // wait: own outstanding = ISSUE(t+1) loads -> ISSUE(t) complete
        if (t < NT-1) {
            if (w < 5) asm volatile("s_waitcnt vmcnt(6)" ::: "memory");
            else       asm volatile("s_waitcnt vmcnt(5)" ::: "memory");
        } else {
            asm volatile("s_waitcnt vmcnt(0)" ::: "memory");
        }
        __builtin_amdgcn_sched_barrier(0);
        __builtin_amdgcn_s_barrier();       // tile t (kt,kmx,vt) visible to all
        __builtin_amdgcn_sched_barrier(0);

        const char* ktb = (const char*)smem + cur*16384;
        const char* kmb = (const char*)smem + 32768 + cur*12288;
        const char* vtb = (const char*)smem + 57344 + cur*17408;
        f32x4 sacc[2];
        sacc[0] = zero; sacc[1] = zero;
        __builtin_amdgcn_s_setprio(1);
        #pragma unroll
        for (int ks = 0; ks < 8; ++ks) {     // ip+s dims, swapped: mfma(K, Q)
            int off = (ks & 1) ? (kbO + (ks-1)*64) : (kbE + ks*64);
            bf16x8 a0 = *(const bf16x8*)(ktb + off);
            bf16x8 a1 = *(const bf16x8*)(ktb + off + 8192);
            sacc[0] = __builtin_amdgcn_mfma_f32_16x16x32_bf16(a0, qip[ks], sacc[0], 0, 0, 0);
            sacc[1] = __builtin_amdgcn_mfma_f32_16x16x32_bf16(a1, qip[ks], sacc[1], 0, 0, 0);
        }
        #pragma unroll
        for (int ct = 0; ct < 2; ++ct) {     // dist split-precision, dup-block scheme
            const char* kk = kmb + ct*6144;
            bf16x8 ka0 = *(const bf16x8*)(kk + mA);
            bf16x8 ka1 = *(const bf16x8*)(kk + mB);
            bf16x8 ka2 = *(const bf16x8*)(kk + mA + 128);
            bf16x8 kb0 = *(const bf16x8*)(kk + mB + 128);
            bf16x8 kb1 = *(const bf16x8*)(kk + mA + 256);
            bf16x8 kb2 = *(const bf16x8*)(kk + mB + 256);
            f32x4 a = sacc[ct];
            a = __builtin_amdgcn_mfma_f32_16x16x32_bf16(ka0, qdx[0], a, 0, 0, 0); // qh.km head
            a = __builtin_amdgcn_mfma_f32_16x16x32_bf16(ka1, qdx[1], a, 0, 0, 0); // qh.km tail + qh.kl head
            a = __builtin_amdgcn_mfma_f32_16x16x32_bf16(ka2, qdx[2], a, 0, 0, 0); // qh.kl tail
            a = __builtin_amdgcn_mfma_f32_16x16x32_bf16(kb0, qdx[3], a, 0, 0, 0); // qm.kh head
            a = __builtin_amdgcn_mfma_f32_16x16x32_bf16(kb1, qdx[4], a, 0, 0, 0); // qm.kh tail + ql.kh head
            a = __builtin_amdgcn_mfma_f32_16x16x32_bf16(kb2, qdx[5], a, 0, 0, 0); // ql.kh tail
            a = __builtin_amdgcn_mfma_f32_16x16x32_bf16(ka0, qdx[3], a, 0, 0, 0); // qm.km head
            a = __builtin_amdgcn_mfma_f32_16x16x32_bf16(ka1, qdx[6], a, 0, 0, 0); // qm.km tail (z-kill)
            a = __builtin_amdgcn_mfma_f32_16x16x32_bf16(kb0, qdx[0], a, 0, 0, 0); // qh.kh head
            a = __builtin_amdgcn_mfma_f32_16x16x32_bf16(kb1, qdx[7], a, 0, 0, 0); // qh.kh tail (z-kill)
            sacc[ct] = a;
        }
        __builtin_amdgcn_s_setprio(0);

        // online softmax, per-lane q=l15; defer-max THR=8
        float pm = fmaxf(fmaxf(fmaxf(sacc[0][0], sacc[0][1]), fmaxf(sacc[0][2], sacc[0][3])),
                         fmaxf(fmaxf(sacc[1][0], sacc[1][1]), fmaxf(sacc[1][2], sacc[1][3])));
        pm = fmaxf(pm, __shfl_xor(pm, 16, 64));
        pm = fmaxf(pm, __shfl_xor(pm, 32, 64));
        if (!__all(pm <= mreg + 8.0f)) {
            float mnew = fmaxf(mreg, pm);
            float al = __expf(mreg - mnew);      // 0 on first tile
            mreg = mnew;
            lreg *= al;
            float a0 = __shfl(al, l4*4+0, 64);
            float a1 = __shfl(al, l4*4+1, 64);
            float a2 = __shfl(al, l4*4+2, 64);
            float a3 = __shfl(al, l4*4+3, 64);
            #pragma unroll
            for (int ct = 0; ct < 17; ++ct) {
                oacc[ct][0] *= a0; oacc[ct][1] *= a1;
                oacc[ct][2] *= a2; oacc[ct][3] *= a3;
            }
        }
        float p0 = __expf(sacc[0][0] - mreg), p1 = __expf(sacc[0][1] - mreg);
        float p2 = __expf(sacc[0][2] - mreg), p3 = __expf(sacc[0][3] - mreg);
        float p4 = __expf(sacc[1][0] - mreg), p5 = __expf(sacc[1][1] - mreg);
        float p6 = __expf(sacc[1][2] - mreg), p7 = __expf(sacc[1][3] - mreg);
        lreg += ((p0 + p1) + (p2 + p3)) + ((p4 + p5) + (p6 + p7));
        unsigned r01, r23, r45, r67;
        asm("v_cvt_pk_bf16_f32 %0, %1, %2" : "=v"(r01) : "v"(p0), "v"(p1));
        asm("v_cvt_pk_bf16_f32 %0, %1, %2" : "=v"(r23) : "v"(p2), "v"(p3));
        asm("v_cvt_pk_bf16_f32 %0, %1, %2" : "=v"(r45) : "v"(p4), "v"(p5));
        asm("v_cvt_pk_bf16_f32 %0, %1, %2" : "=v"(r67) : "v"(p6), "v"(p7));
        {
            char* pbp = (char*)smem;
            *(unsigned*)(pbp + pSeg0 + 0) = r01;
            *(unsigned*)(pbp + pSeg0 + 4) = r23;
            *(unsigned*)(pbp + pSeg1 + 0) = r45;
            *(unsigned*)(pbp + pSeg1 + 4) = r67;
        }

        // PV directly: P is wave-private (compiler orders ds_write->ds_read);
        // vt(t) visibility was established by the mid-tile barrier.
        {
            bf16x8 pa = *(const bf16x8*)((const char*)smem + pRd);
            __builtin_amdgcn_s_setprio(1);
            #pragma unroll
            for (int ct = 0; ct < 17; ++ct) {
                bf16x8 bv = *(const bf16x8*)(vtb + vlane + ct*1024);
                oacc[ct] = __builtin_amdgcn_mfma_f32_16x16x32_bf16(pa, bv, oacc[ct], 0, 0, 0);
            }
            __builtin_amdgcn_s_setprio(0);
        }
        __builtin_amdgcn_s_barrier();        // all waves done reading tile t
        __builtin_amdgcn_sched_barrier(0);
        cur ^= 1;
    }
#undef ISSUE

    // epilogue: finish deferred l, scatter
    float lf = lreg;
    lf += __shfl_xor(lf, 16, 64);
    lf += __shfl_xor(lf, 32, 64);
    const size_t mv_total = (size_t)HH * NN * 256;
    #pragma unroll
    for (int j = 0; j < 4; ++j) {
        float inv = 1.0f / __shfl(lf, l4*4 + j, 64);
        int q = q0 + w*16 + l4*4 + j;
        float* po = out + ((size_t)h*NN + q) * 256 + l15;
        #pragma unroll
        for (int ct = 0; ct < 16; ++ct)
            po[ct*16] = oacc[ct][j] * inv;
        out[mv_total + ((size_t)h*NN + q)*16 + l15] = oacc[16][j] * inv;
    }
}

extern "C" void kernel_launch(void* const* d_in, const int* in_sizes, int n_in,
                              void* d_out, int out_size, void* d_ws, size_t ws_size,
                              hipStream_t stream)
{
    const float* q_mv = (const float*)d_in[0];
    const float* k_mv = (const float*)d_in[1];
    const float* v_mv = (const float*)d_in[2];
    const float* q_s  = (const float*)d_in[3];
    const float* k_s  = (const float*)d_in[4];
    const float* v_s  = (const float*)d_in[5];
    const float* basis_q = (const float*)d_in[6];
    const float* basis_k = (const float*)d_in[7];
    float* out = (float*)d_out;

    unsigned short* qip = (unsigned short*)d_ws;                 // [8][4096][256]
    unsigned short* qdx = qip + (size_t)HH*NN*DIP;               // [8][4096][256]
    unsigned short* kip = qdx + (size_t)HH*NN*DDX;               // [8][4096][256]
    unsigned short* kmx = kip + (size_t)HH*NN*DIP;               // [8][4096][192]
    unsigned short* vt  = kmx + (size_t)HH*NN*DKM;               // [8][272][4096]
    // total ws use: 80,740,352 bytes

    const float qscale = 0.05735393346764042f;  // 1/sqrt(304); k-rescale is exactly 1

    feat_kernel<<<dim3(1024), dim3(256), 0, stream>>>(q_mv, q_s, basis_q, qscale, 1, qip, qdx);
    feat_kernel<<<dim3(1024), dim3(256), 0, stream>>>(k_mv, k_s, basis_k, 1.0f,   0, kip, kmx);
    vtrans_kernel<<<dim3(512), dim3(256), 0, stream>>>(v_mv, v_s, vt);
    attn_kernel<<<dim3(256), dim3(512), 0, stream>>>(qip, qdx, kip, kmx, vt, out);
}